// Round 4
// baseline (41.109 us; speedup 1.0000x reference)
//
#include <hip/hip_runtime.h>

// GD_lagrange_multi fused kernel for MI355X (gfx950).  Round 4: software pipeline.
// Shapes fixed by setup_inputs(): W=4, B=32, S=16, G=1024, niter=20.
// One block per (w,b): 512 threads = 8 waves, wave owns 128 g-rows = 8 MFMA tiles.
//
// Lane layout (per 16x16 tile), lane l = 16*q + m:
//   Om[t][r]   = Omega[g0+16t+4q+r][j=m]      (C/D layout, f32 master)
//   OmB frag e = Omega[g0+16t+4q+e][j=m]      (B-frag, k=g)
//   YpB[t]  e  = Yp[i=m][g0+16t+4q+e]         (A-frag, k=g)
//   YpA[t]  e  = Yp[s=4q+e][g0+16t+m]         (A-frag, k=s)
//   lamB    e  = lam[s=4q+e][j=m]             (B-frag, k=s)
// mfma(YpB,OmB) -> (Yp@Omega)[4q+r][m]: write pattern == read pattern for the
// cross-wave reduce (no transpose).  mfma(YpA,lamB) -> (Yp^T@lam) in master layout.
//
// Pipeline (per body, producing state i+1 from state i):
//   HOT : pack lamB_i; 8x mfma go; Om' = Om - mu*(nrm_i + go); pack; 8x chained
//         mfma PhaseB(Om'); lam_{i+1} += ro*(gsum_i - tgt)   [reads long done]
//   SYNC: ds_write partial; s_waitcnt lgkmcnt(0); barrier; issue 8 ds_reads
//   SHAD: nrm_{i+1} = Om'/||Om'||  (128 DPP + 32 rsq, hides read latency; its
//         own latency hidden -- nothing consumes nrm until next body)

typedef float    f32x4 __attribute__((ext_vector_type(4)));
typedef _Float16 f16x4 __attribute__((ext_vector_type(4)));
typedef __fp16   h16x2 __attribute__((ext_vector_type(2)));

#define MUv 1e-3f
#define ROv 1e-3f

#define ROR_ADD(s, CTRL)                                                      \
  s += __int_as_float(__builtin_amdgcn_update_dpp(                            \
      0, __float_as_int(s), (CTRL), 0xF, 0xF, true))

__device__ __forceinline__ float rowsum16(float x) {
  float s = x;
  ROR_ADD(s, 0x128);  // row_ror:8
  ROR_ADD(s, 0x124);  // row_ror:4
  ROR_ADD(s, 0x122);  // row_ror:2
  ROR_ADD(s, 0x121);  // row_ror:1
  return s;
}

__device__ __forceinline__ f16x4 pack4(float a, float b, float c, float d) {
  h16x2 lo = __builtin_amdgcn_cvt_pkrtz(a, b);
  h16x2 hi = __builtin_amdgcn_cvt_pkrtz(c, d);
  union { struct { h16x2 lo, hi; } p; f16x4 v; } u;
  u.p.lo = lo; u.p.hi = hi;
  return u.v;
}

__global__ __launch_bounds__(512) void gd_lagrange_kernel(
    const float* __restrict__ Yp,   // [128][16][1024]
    const float* __restrict__ Uk,   // [128][16][16]
    const float* __restrict__ Lm,   // [128][16][16]
    const float* __restrict__ Om0,  // [128][1024][16]
    const int* __restrict__ nitp,   // [1]
    float* __restrict__ out) {      // [128][1024][16]
  constexpr int S = 16, G = 1024;
  constexpr int YP_LD = 1028;  // pad: frag reads <=2-way banked, 16B-aligned rows
  constexpr int RPAD  = 20;    // reduce-buffer row pitch (words)

  const int wb  = blockIdx.x;
  const int tid = threadIdx.x;
  const int wv  = tid >> 6;
  const int q   = (tid >> 4) & 3;
  const int m   = tid & 15;
  const int g0  = wv * 128;

  __shared__ float ldsYp[S * YP_LD];
  __shared__ float ldsRed[2][8][S * RPAD];
  __shared__ float ldsUk[S * S];
  __shared__ float ldsLm[S * S];

  const float* ypg = Yp + (size_t)wb * (S * G);

  // ---- stage Yp slice ----
  #pragma unroll
  for (int k = 0; k < 8; ++k) {
    int vi  = k * 512 + tid;
    f32x4 v = ((const f32x4*)ypg)[vi];
    int row = vi >> 8;
    int col = (vi & 255) * 4;
    *(f32x4*)&ldsYp[row * YP_LD + col] = v;
  }
  if (tid < 256) {
    ldsUk[tid] = Uk[wb * 256 + tid];
    ldsLm[tid] = Lm[wb * 256 + tid];
  }
  __syncthreads();

  // ---- static Yp fragments (f16) ----
  f16x4 YpA[8], YpB[8];
  #pragma unroll
  for (int t = 0; t < 8; ++t) {
    int gt = g0 + 16 * t;
    YpB[t] = pack4(ldsYp[m * YP_LD + gt + 4 * q + 0],
                   ldsYp[m * YP_LD + gt + 4 * q + 1],
                   ldsYp[m * YP_LD + gt + 4 * q + 2],
                   ldsYp[m * YP_LD + gt + 4 * q + 3]);
    YpA[t] = pack4(ldsYp[(4 * q + 0) * YP_LD + gt + m],
                   ldsYp[(4 * q + 1) * YP_LD + gt + m],
                   ldsYp[(4 * q + 2) * YP_LD + gt + m],
                   ldsYp[(4 * q + 3) * YP_LD + gt + m]);
  }

  // ---- Omega master (f32) ----
  float Om[8][4];
  const float* omg = Om0 + (size_t)wb * (G * S);
  #pragma unroll
  for (int t = 0; t < 8; ++t)
    #pragma unroll
    for (int r = 0; r < 4; ++r)
      Om[t][r] = omg[(g0 + 16 * t + 4 * q + r) * S + m];

  // ---- target: tgt[e] = (Uk@Lambda)[4q+e][m] ----
  float tgt[4];
  #pragma unroll
  for (int e = 0; e < 4; ++e) {
    float s = 0.f;
    for (int k = 0; k < 16; ++k)
      s += ldsUk[(4 * q + e) * 16 + k] * ldsLm[k * 16 + m];
    tgt[e] = s;
  }

  float lam32[4] = {0.f, 0.f, 0.f, 0.f};
  const int niter = nitp[0];
  const int rslot = m * RPAD + 4 * q;

  // ---- nrm_0 = Om_0 / ||row|| ----
  float nrm[8][4];
  #pragma unroll
  for (int t = 0; t < 8; ++t)
    #pragma unroll
    for (int r = 0; r < 4; ++r) {
      float x  = Om[t][r];
      float n2 = rowsum16(x * x);
      nrm[t][r] = x * __builtin_amdgcn_rsqf(n2);
    }

  // ---- Phase B(0): partial Yp@Om_0, single accumulate chain ----
  {
    f32x4 accB = {0.f, 0.f, 0.f, 0.f};
    #pragma unroll
    for (int t = 0; t < 8; ++t)
      accB = __builtin_amdgcn_mfma_f32_16x16x16f16(
          YpB[t], pack4(Om[t][0], Om[t][1], Om[t][2], Om[t][3]), accB, 0, 0, 0);
    *(f32x4*)&ldsRed[0][wv][rslot] = accB;
  }
  asm volatile("s_waitcnt lgkmcnt(0)" ::: "memory");
  __syncthreads();
  f32x4 part[8];
  #pragma unroll
  for (int w2 = 0; w2 < 8; ++w2)
    part[w2] = *(const f32x4*)&ldsRed[0][w2][rslot];

  int wbuf = 1;
  for (int it = 0; it < niter; ++it) {
    // ===== HOT =====
    f16x4 lamB = pack4(lam32[0], lam32[1], lam32[2], lam32[3]);
    f32x4 accN = {0.f, 0.f, 0.f, 0.f};
    #pragma unroll
    for (int t = 0; t < 8; ++t) {
      f32x4 z = {0.f, 0.f, 0.f, 0.f};
      f32x4 go = __builtin_amdgcn_mfma_f32_16x16x16f16(YpA[t], lamB, z, 0, 0, 0);
      #pragma unroll
      for (int r = 0; r < 4; ++r) {
        float u  = nrm[t][r] + go[r];
        Om[t][r] = fmaf(-MUv, u, Om[t][r]);
      }
      accN = __builtin_amdgcn_mfma_f32_16x16x16f16(
          YpB[t], pack4(Om[t][0], Om[t][1], Om[t][2], Om[t][3]), accN, 0, 0, 0);
    }

    // lam_{i+1} from gsum_i (reads issued last body; long complete)
    f32x4 gsum = ((part[0] + part[1]) + (part[2] + part[3])) +
                 ((part[4] + part[5]) + (part[6] + part[7]));
    #pragma unroll
    for (int e = 0; e < 4; ++e)
      lam32[e] += ROv * (gsum[e] - tgt[e]);

    // ===== SYNC =====
    *(f32x4*)&ldsRed[wbuf][wv][rslot] = accN;
    asm volatile("s_waitcnt lgkmcnt(0)" ::: "memory");  // pin consumption pre-barrier
    __syncthreads();
    #pragma unroll
    for (int w2 = 0; w2 < 8; ++w2)
      part[w2] = *(const f32x4*)&ldsRed[wbuf][w2][rslot];

    // ===== SHADOW: nrm_{i+1} (hides read latency; consumed next body) =====
    #pragma unroll
    for (int t = 0; t < 8; ++t)
      #pragma unroll
      for (int r = 0; r < 4; ++r) {
        float x  = Om[t][r];
        float n2 = rowsum16(x * x);
        nrm[t][r] = x * __builtin_amdgcn_rsqf(n2);
      }

    wbuf ^= 1;
  }

  // ---- store Omega ----
  float* og = out + (size_t)wb * (G * S);
  #pragma unroll
  for (int t = 0; t < 8; ++t)
    #pragma unroll
    for (int r = 0; r < 4; ++r)
      og[(g0 + 16 * t + 4 * q + r) * S + m] = Om[t][r];
}

extern "C" void kernel_launch(void* const* d_in, const int* in_sizes, int n_in,
                              void* d_out, int out_size, void* d_ws, size_t ws_size,
                              hipStream_t stream) {
  const float* Yp  = (const float*)d_in[0];
  const float* Uk  = (const float*)d_in[1];
  const float* Lm  = (const float*)d_in[2];
  const float* Om0 = (const float*)d_in[3];
  const int*   nit = (const int*)d_in[4];
  float* out = (float*)d_out;

  gd_lagrange_kernel<<<dim3(128), dim3(512), 0, stream>>>(Yp, Uk, Lm, Om0, nit, out);
}

// Round 5
// 39.570 us; speedup vs baseline: 1.0389x; 1.0389x over previous
//
#include <hip/hip_runtime.h>

// GD_lagrange_multi fused kernel for MI355X (gfx950).  Round 5.
// Shapes: W=4, B=32, S=16, G=1024, niter=20. One block per (w,b): 8 waves,
// wave owns 128 g-rows = 8 MFMA tiles (16x16x16 f16, f32 accum).
//
// Lane layout (per tile), lane l = 16q + m:
//   Om[t][r]   = Omega[g0+16t+4q+r][j=m]      (C/D layout, f32 master)
//   OmB frag e = Omega[g0+16t+4q+e][j=m]      (B-frag, k=g)
//   YpB[t]  e  = Yp[i=m][g0+16t+4q+e]         (A-frag, k=g)
//   YpA[t]  e  = Yp[s=4q+e][g0+16t+m]         (A-frag, k=s)
//   lamB    e  = lam[s=4q+e][j=m]             (B-frag, k=s)
// mfma(YpB,OmB) -> (Yp@Omega)[4q+r][m]: write pattern == read pattern for the
// cross-wave reduce -> ANY per-lane slot placement works; use lane*16B
// contiguous (conflict-free b128, the R4 8-way-conflict fix).
//
// Pipeline per body i (state i -> i+1):
//   HOT : pack lamB_i; 8x mfma go (indep); Om_{i+1} = OmPre_i - mu*go
//         (OmPre_i = Om_i - mu*nrm_i, from SHADOW); 4-chain mfma PhaseB(Om_{i+1});
//         ds_write partial; lam_{i+1} += ro*(gsum_i - tgt); barrier
//   POST: issue 8 conflict-free ds_reads (consumed next body)
//   SHAD: nrm/OmPre_{i+1} (hides read latency + DS-pipe burst)

typedef float    f32x4 __attribute__((ext_vector_type(4)));
typedef _Float16 f16x4 __attribute__((ext_vector_type(4)));
typedef __fp16   h16x2 __attribute__((ext_vector_type(2)));

#define MUv 1e-3f
#define ROv 1e-3f

#define ROR_ADD(s, CTRL)                                                      \
  s += __int_as_float(__builtin_amdgcn_update_dpp(                            \
      0, __float_as_int(s), (CTRL), 0xF, 0xF, true))

__device__ __forceinline__ float rowsum16(float x) {
  float s = x;
  ROR_ADD(s, 0x128);  // row_ror:8
  ROR_ADD(s, 0x124);  // row_ror:4
  ROR_ADD(s, 0x122);  // row_ror:2
  ROR_ADD(s, 0x121);  // row_ror:1
  return s;
}

__device__ __forceinline__ f16x4 pack4(float a, float b, float c, float d) {
  h16x2 lo = __builtin_amdgcn_cvt_pkrtz(a, b);
  h16x2 hi = __builtin_amdgcn_cvt_pkrtz(c, d);
  union { struct { h16x2 lo, hi; } p; f16x4 v; } u;
  u.p.lo = lo; u.p.hi = hi;
  return u.v;
}

__global__ __launch_bounds__(512) void gd_lagrange_kernel(
    const float* __restrict__ Yp,   // [128][16][1024]
    const float* __restrict__ Uk,   // [128][16][16]
    const float* __restrict__ Lm,   // [128][16][16]
    const float* __restrict__ Om0,  // [128][1024][16]
    const int* __restrict__ nitp,   // [1]
    float* __restrict__ out) {      // [128][1024][16]
  constexpr int S = 16, G = 1024;
  constexpr int YP_LD = 1028;

  const int wb   = blockIdx.x;
  const int tid  = threadIdx.x;
  const int wv   = tid >> 6;
  const int lane = tid & 63;
  const int q    = (tid >> 4) & 3;
  const int m    = tid & 15;
  const int g0   = wv * 128;

  __shared__ float ldsYp[S * YP_LD];
  __shared__ float ldsRed[2][8][256];   // lane-contiguous b128 slots, 16 KB
  __shared__ float ldsUk[S * S];
  __shared__ float ldsLm[S * S];

  const float* ypg = Yp + (size_t)wb * (S * G);

  // ---- stage Yp slice ----
  #pragma unroll
  for (int k = 0; k < 8; ++k) {
    int vi  = k * 512 + tid;
    f32x4 v = ((const f32x4*)ypg)[vi];
    int row = vi >> 8;
    int col = (vi & 255) * 4;
    *(f32x4*)&ldsYp[row * YP_LD + col] = v;
  }
  if (tid < 256) {
    ldsUk[tid] = Uk[wb * 256 + tid];
    ldsLm[tid] = Lm[wb * 256 + tid];
  }
  __syncthreads();

  // ---- static Yp fragments (f16) ----
  f16x4 YpA[8], YpB[8];
  #pragma unroll
  for (int t = 0; t < 8; ++t) {
    int gt = g0 + 16 * t;
    YpB[t] = pack4(ldsYp[m * YP_LD + gt + 4 * q + 0],
                   ldsYp[m * YP_LD + gt + 4 * q + 1],
                   ldsYp[m * YP_LD + gt + 4 * q + 2],
                   ldsYp[m * YP_LD + gt + 4 * q + 3]);
    YpA[t] = pack4(ldsYp[(4 * q + 0) * YP_LD + gt + m],
                   ldsYp[(4 * q + 1) * YP_LD + gt + m],
                   ldsYp[(4 * q + 2) * YP_LD + gt + m],
                   ldsYp[(4 * q + 3) * YP_LD + gt + m]);
  }

  // ---- Omega master (f32) ----
  float Om[8][4];
  const float* omg = Om0 + (size_t)wb * (G * S);
  #pragma unroll
  for (int t = 0; t < 8; ++t)
    #pragma unroll
    for (int r = 0; r < 4; ++r)
      Om[t][r] = omg[(g0 + 16 * t + 4 * q + r) * S + m];

  // ---- target: tgt[e] = (Uk@Lambda)[4q+e][m] ----
  float tgt[4];
  #pragma unroll
  for (int e = 0; e < 4; ++e) {
    float s = 0.f;
    for (int k = 0; k < 16; ++k)
      s += ldsUk[(4 * q + e) * 16 + k] * ldsLm[k * 16 + m];
    tgt[e] = s;
  }

  float lam32[4] = {0.f, 0.f, 0.f, 0.f};
  const int niter = nitp[0];
  const int rslot = lane * 4;   // conflict-free b128 slot

  // ---- OmPre_0 = Om_0 - mu * Om_0/||row|| ----
  float OmPre[8][4];
  #pragma unroll
  for (int t = 0; t < 8; ++t)
    #pragma unroll
    for (int r = 0; r < 4; ++r) {
      float x  = Om[t][r];
      float n2 = rowsum16(x * x);
      float nr = x * __builtin_amdgcn_rsqf(n2);
      OmPre[t][r] = fmaf(-MUv, nr, x);
    }

  // ---- Phase B(0): partial Yp@Om_0 (OLD Om) ----
  {
    f32x4 a0 = {0.f, 0.f, 0.f, 0.f}, a1 = {0.f, 0.f, 0.f, 0.f};
    #pragma unroll
    for (int t = 0; t < 8; t += 2) {
      a0 = __builtin_amdgcn_mfma_f32_16x16x16f16(
          YpB[t], pack4(Om[t][0], Om[t][1], Om[t][2], Om[t][3]), a0, 0, 0, 0);
      a1 = __builtin_amdgcn_mfma_f32_16x16x16f16(
          YpB[t + 1], pack4(Om[t + 1][0], Om[t + 1][1], Om[t + 1][2], Om[t + 1][3]), a1, 0, 0, 0);
    }
    *(f32x4*)&ldsRed[0][wv][rslot] = a0 + a1;
  }
  __syncthreads();
  f32x4 part[8];
  #pragma unroll
  for (int w2 = 0; w2 < 8; ++w2)
    part[w2] = *(const f32x4*)&ldsRed[0][w2][rslot];

  int wbuf = 1;
  for (int it = 0; it < niter; ++it) {
    // ===== HOT =====
    f16x4 lamB = pack4(lam32[0], lam32[1], lam32[2], lam32[3]);
    f32x4 acc[4];
    #pragma unroll
    for (int c = 0; c < 4; ++c) acc[c] = (f32x4){0.f, 0.f, 0.f, 0.f};
    #pragma unroll
    for (int t = 0; t < 8; ++t) {
      f32x4 z = {0.f, 0.f, 0.f, 0.f};
      f32x4 go = __builtin_amdgcn_mfma_f32_16x16x16f16(YpA[t], lamB, z, 0, 0, 0);
      #pragma unroll
      for (int r = 0; r < 4; ++r)
        Om[t][r] = fmaf(-MUv, go[r], OmPre[t][r]);     // Om_{i+1}
      acc[t & 3] = __builtin_amdgcn_mfma_f32_16x16x16f16(
          YpB[t], pack4(Om[t][0], Om[t][1], Om[t][2], Om[t][3]), acc[t & 3], 0, 0, 0);
    }
    *(f32x4*)&ldsRed[wbuf][wv][rslot] = (acc[0] + acc[1]) + (acc[2] + acc[3]);

    // lam_{i+1} from gsum_i (reads issued last body, long complete)
    f32x4 gsum = ((part[0] + part[1]) + (part[2] + part[3])) +
                 ((part[4] + part[5]) + (part[6] + part[7]));
    #pragma unroll
    for (int e = 0; e < 4; ++e)
      lam32[e] += ROv * (gsum[e] - tgt[e]);

    __syncthreads();

    // issue conflict-free cross-wave reads (consumed next body)
    #pragma unroll
    for (int w2 = 0; w2 < 8; ++w2)
      part[w2] = *(const f32x4*)&ldsRed[wbuf][w2][rslot];

    // ===== SHADOW: nrm/OmPre_{i+1} =====
    #pragma unroll
    for (int t = 0; t < 8; ++t)
      #pragma unroll
      for (int r = 0; r < 4; ++r) {
        float x  = Om[t][r];
        float n2 = rowsum16(x * x);
        float nr = x * __builtin_amdgcn_rsqf(n2);
        OmPre[t][r] = fmaf(-MUv, nr, x);
      }

    wbuf ^= 1;
  }

  // ---- store Omega ----
  float* og = out + (size_t)wb * (G * S);
  #pragma unroll
  for (int t = 0; t < 8; ++t)
    #pragma unroll
    for (int r = 0; r < 4; ++r)
      og[(g0 + 16 * t + 4 * q + r) * S + m] = Om[t][r];
}

extern "C" void kernel_launch(void* const* d_in, const int* in_sizes, int n_in,
                              void* d_out, int out_size, void* d_ws, size_t ws_size,
                              hipStream_t stream) {
  const float* Yp  = (const float*)d_in[0];
  const float* Uk  = (const float*)d_in[1];
  const float* Lm  = (const float*)d_in[2];
  const float* Om0 = (const float*)d_in[3];
  const int*   nit = (const int*)d_in[4];
  float* out = (float*)d_out;

  gd_lagrange_kernel<<<dim3(128), dim3(512), 0, stream>>>(Yp, Uk, Lm, Om0, nit, out);
}

// Round 6
// 34.091 us; speedup vs baseline: 1.2059x; 1.1607x over previous
//
#include <hip/hip_runtime.h>

// GD_lagrange_multi fused kernel for MI355X (gfx950).  Round 6: MFMA-norm.
// Shapes: W=4, B=32, S=16, G=1024, niter from input. One block per (w,b):
// 8 waves, wave owns 128 g-rows = 8 MFMA tiles (16x16x16 f16, f32 accum).
//
// Lane layout (per tile), lane l = 16q + m:
//   Om[t][r]   = Omega[g0+16t+4q+r][j=m]      (C/D layout, f32 master)
//   OmB frag e = Omega[g0+16t+4q+e][j=m]      (B-frag, k=g)
//   YpB[t]  e  = Yp[i=m][g0+16t+4q+e]         (A-frag, k=g)
//   YpA[t]  e  = Yp[s=4q+e][g0+16t+m]         (A-frag, k=s)
//   lamB    e  = lam[s=4q+e][j=m]             (B-frag, k=s)
// mfma(YpB,OmB) -> (Yp@Omega)[4q+r][m]: write pattern == read pattern for the
// cross-wave reduce -> lane-contiguous b128 slots (conflict-free).
//
// MFMA-norm (replaces DPP rowsums, moves ~130 VALU ops/wave/iter to the idle
// MFMA pipe): OmSq = OmB*OmB (v_pk_mul_f16). Master-layout OmSq fed as A-frag
// represents OmSq^T, so D1 = mfma(OmSq, I) = OmSq^T (transposed tile, f32 but
// f16-exact). T1 = pack(D1) fed as A-frag represents OmSq with k=j, so
// D2 = mfma(T1, ones) has D2 elem r = n2[g=4q+r] -- exactly the master slot.
// Then OmPre = Om * (1 - mu*rsq(n2)) folds the norm-gradient term.

typedef float    f32x4 __attribute__((ext_vector_type(4)));
typedef _Float16 f16x4 __attribute__((ext_vector_type(4)));
typedef __fp16   h16x2 __attribute__((ext_vector_type(2)));

#define MUv 1e-3f
#define ROv 1e-3f

__device__ __forceinline__ f16x4 pack4(float a, float b, float c, float d) {
  h16x2 lo = __builtin_amdgcn_cvt_pkrtz(a, b);
  h16x2 hi = __builtin_amdgcn_cvt_pkrtz(c, d);
  union { struct { h16x2 lo, hi; } p; f16x4 v; } u;
  u.p.lo = lo; u.p.hi = hi;
  return u.v;
}

__global__ __launch_bounds__(512) void gd_lagrange_kernel(
    const float* __restrict__ Yp,   // [128][16][1024]
    const float* __restrict__ Uk,   // [128][16][16]
    const float* __restrict__ Lm,   // [128][16][16]
    const float* __restrict__ Om0,  // [128][1024][16]
    const int* __restrict__ nitp,   // [1]
    float* __restrict__ out) {      // [128][1024][16]
  constexpr int S = 16, G = 1024;
  constexpr int YP_LD = 1028;

  const int wb   = blockIdx.x;
  const int tid  = threadIdx.x;
  const int wv   = tid >> 6;
  const int lane = tid & 63;
  const int q    = (tid >> 4) & 3;
  const int m    = tid & 15;
  const int g0   = wv * 128;

  __shared__ float ldsYp[S * YP_LD];
  __shared__ float ldsRed[2][8][256];   // lane-contiguous b128 slots
  __shared__ float ldsUk[S * S];
  __shared__ float ldsLm[S * S];

  const float* ypg = Yp + (size_t)wb * (S * G);

  // ---- stage Yp slice ----
  #pragma unroll
  for (int k = 0; k < 8; ++k) {
    int vi  = k * 512 + tid;
    f32x4 v = ((const f32x4*)ypg)[vi];
    int row = vi >> 8;
    int col = (vi & 255) * 4;
    *(f32x4*)&ldsYp[row * YP_LD + col] = v;
  }
  if (tid < 256) {
    ldsUk[tid] = Uk[wb * 256 + tid];
    ldsLm[tid] = Lm[wb * 256 + tid];
  }
  __syncthreads();

  // ---- static frags: identity (B: I[4q+e][m]) and ones ----
  f16x4 Ifrag, ones1;
  #pragma unroll
  for (int e = 0; e < 4; ++e) {
    Ifrag[e] = (4 * q + e == m) ? (_Float16)1.0f : (_Float16)0.0f;
    ones1[e] = (_Float16)1.0f;
  }

  // ---- static Yp fragments (f16) ----
  f16x4 YpA[8], YpB[8];
  #pragma unroll
  for (int t = 0; t < 8; ++t) {
    int gt = g0 + 16 * t;
    YpB[t] = pack4(ldsYp[m * YP_LD + gt + 4 * q + 0],
                   ldsYp[m * YP_LD + gt + 4 * q + 1],
                   ldsYp[m * YP_LD + gt + 4 * q + 2],
                   ldsYp[m * YP_LD + gt + 4 * q + 3]);
    YpA[t] = pack4(ldsYp[(4 * q + 0) * YP_LD + gt + m],
                   ldsYp[(4 * q + 1) * YP_LD + gt + m],
                   ldsYp[(4 * q + 2) * YP_LD + gt + m],
                   ldsYp[(4 * q + 3) * YP_LD + gt + m]);
  }

  // ---- Omega master (f32) ----
  float Om[8][4];
  const float* omg = Om0 + (size_t)wb * (G * S);
  #pragma unroll
  for (int t = 0; t < 8; ++t)
    #pragma unroll
    for (int r = 0; r < 4; ++r)
      Om[t][r] = omg[(g0 + 16 * t + 4 * q + r) * S + m];

  // ---- target: tgt[e] = (Uk@Lambda)[4q+e][m] ----
  float tgt[4];
  #pragma unroll
  for (int e = 0; e < 4; ++e) {
    float s = 0.f;
    for (int k = 0; k < 16; ++k)
      s += ldsUk[(4 * q + e) * 16 + k] * ldsLm[k * 16 + m];
    tgt[e] = s;
  }

  float lam32[4] = {0.f, 0.f, 0.f, 0.f};
  const int niter = nitp[0];
  const int rslot = lane * 4;

  // ---- MFMA-norm of Om_0 -> OmPre_0 ----
  float OmPre[8][4];
  f16x4 OmB[8];
  #pragma unroll
  for (int t = 0; t < 8; ++t)
    OmB[t] = pack4(Om[t][0], Om[t][1], Om[t][2], Om[t][3]);
  #pragma unroll
  for (int t = 0; t < 8; ++t) {
    f32x4 z = {0.f, 0.f, 0.f, 0.f};
    f16x4 sq = OmB[t] * OmB[t];                                   // v_pk_mul_f16
    f32x4 d1 = __builtin_amdgcn_mfma_f32_16x16x16f16(sq, Ifrag, z, 0, 0, 0);
    f16x4 t1 = pack4(d1[0], d1[1], d1[2], d1[3]);                 // f16-exact
    f32x4 n2 = __builtin_amdgcn_mfma_f32_16x16x16f16(t1, ones1, z, 0, 0, 0);
    #pragma unroll
    for (int r = 0; r < 4; ++r) {
      float s = fmaf(-MUv, __builtin_amdgcn_rsqf(n2[r]), 1.0f);
      OmPre[t][r] = Om[t][r] * s;
    }
  }

  // ---- Phase B(0): partial Yp@Om_0 (OLD Om) ----
  {
    f32x4 a0 = {0.f, 0.f, 0.f, 0.f}, a1 = {0.f, 0.f, 0.f, 0.f};
    #pragma unroll
    for (int t = 0; t < 8; t += 2) {
      a0 = __builtin_amdgcn_mfma_f32_16x16x16f16(YpB[t], OmB[t], a0, 0, 0, 0);
      a1 = __builtin_amdgcn_mfma_f32_16x16x16f16(YpB[t + 1], OmB[t + 1], a1, 0, 0, 0);
    }
    *(f32x4*)&ldsRed[0][wv][rslot] = a0 + a1;
  }
  __syncthreads();
  f32x4 part[8];
  #pragma unroll
  for (int w2 = 0; w2 < 8; ++w2)
    part[w2] = *(const f32x4*)&ldsRed[0][w2][rslot];

  int wbuf = 1;
  for (int it = 0; it < niter; ++it) {
    // ===== HOT =====
    f16x4 lamB = pack4(lam32[0], lam32[1], lam32[2], lam32[3]);
    f32x4 acc[4];
    #pragma unroll
    for (int c = 0; c < 4; ++c) acc[c] = (f32x4){0.f, 0.f, 0.f, 0.f};
    #pragma unroll
    for (int t = 0; t < 8; ++t) {
      f32x4 z = {0.f, 0.f, 0.f, 0.f};
      f32x4 go = __builtin_amdgcn_mfma_f32_16x16x16f16(YpA[t], lamB, z, 0, 0, 0);
      #pragma unroll
      for (int r = 0; r < 4; ++r)
        Om[t][r] = fmaf(-MUv, go[r], OmPre[t][r]);     // Om_{i+1}
      OmB[t] = pack4(Om[t][0], Om[t][1], Om[t][2], Om[t][3]);
      acc[t & 3] = __builtin_amdgcn_mfma_f32_16x16x16f16(YpB[t], OmB[t], acc[t & 3], 0, 0, 0);
    }
    *(f32x4*)&ldsRed[wbuf][wv][rslot] = (acc[0] + acc[1]) + (acc[2] + acc[3]);

    // lam_{i+1} from gsum_i (reads issued last body, long complete)
    f32x4 gsum = ((part[0] + part[1]) + (part[2] + part[3])) +
                 ((part[4] + part[5]) + (part[6] + part[7]));
    #pragma unroll
    for (int e = 0; e < 4; ++e)
      lam32[e] += ROv * (gsum[e] - tgt[e]);

    __syncthreads();

    // issue conflict-free cross-wave reads (consumed next body)
    #pragma unroll
    for (int w2 = 0; w2 < 8; ++w2)
      part[w2] = *(const f32x4*)&ldsRed[wbuf][w2][rslot];

    // ===== SHADOW: MFMA-norm of Om_{i+1} -> OmPre_{i+1} =====
    #pragma unroll
    for (int t = 0; t < 8; ++t) {
      f32x4 z = {0.f, 0.f, 0.f, 0.f};
      f16x4 sq = OmB[t] * OmB[t];
      f32x4 d1 = __builtin_amdgcn_mfma_f32_16x16x16f16(sq, Ifrag, z, 0, 0, 0);
      f16x4 t1 = pack4(d1[0], d1[1], d1[2], d1[3]);
      f32x4 n2 = __builtin_amdgcn_mfma_f32_16x16x16f16(t1, ones1, z, 0, 0, 0);
      #pragma unroll
      for (int r = 0; r < 4; ++r) {
        float s = fmaf(-MUv, __builtin_amdgcn_rsqf(n2[r]), 1.0f);
        OmPre[t][r] = Om[t][r] * s;
      }
    }

    wbuf ^= 1;
  }

  // ---- store Omega ----
  float* og = out + (size_t)wb * (G * S);
  #pragma unroll
  for (int t = 0; t < 8; ++t)
    #pragma unroll
    for (int r = 0; r < 4; ++r)
      og[(g0 + 16 * t + 4 * q + r) * S + m] = Om[t][r];
}

extern "C" void kernel_launch(void* const* d_in, const int* in_sizes, int n_in,
                              void* d_out, int out_size, void* d_ws, size_t ws_size,
                              hipStream_t stream) {
  const float* Yp  = (const float*)d_in[0];
  const float* Uk  = (const float*)d_in[1];
  const float* Lm  = (const float*)d_in[2];
  const float* Om0 = (const float*)d_in[3];
  const int*   nit = (const int*)d_in[4];
  float* out = (float*)d_out;

  gd_lagrange_kernel<<<dim3(128), dim3(512), 0, stream>>>(Yp, Uk, Lm, Om0, nit, out);
}

// Round 7
// 30.827 us; speedup vs baseline: 1.3335x; 1.1059x over previous
//
#include <hip/hip_runtime.h>

// GD_lagrange_multi fused kernel for MI355X (gfx950).  Round 7: MFMA-folded
// norm + fused-accumulate updates (trans-pipe and VALU issue reduction).
// Shapes: W=4, B=32, S=16, G=1024. One block per (w,b): 8 waves, wave owns
// 128 g-rows = 8 MFMA tiles (16x16x16 f16, f32 accum).
//
// Lane layout (per tile), lane l = 16q + m:
//   Om[t]    r = Omega[g0+16t+4q+r][j=m]      (C/D layout, f32 master)
//   OmB[t]   e = Omega[g0+16t+4q+e][j=m]      (B-frag, k=g)
//   YpB[t]   e = Yp[i=m][g0+16t+4q+e]         (A-frag, k=g)
//   YpA[t]   e = Yp[s=4q+e][g0+16t+m]         (A-frag, k=s)
//   lamN_B   e = (-mu*lam)[s=4q+e][j=m]       (B-frag, k=s)
// Updates as fused MFMAs:
//   Om_{i+1} = mfma(YpA, lamN_B, C=OmPre_i)          (grad step, C-fused)
//   OmPre    = mfma(u*I_A, OmB, C=Om), u=-mu*rsq(n2) (row-scale, C-fused)
// Norm via 3 MFMAs per tile:
//   d1 = mfma(sq_A, I_B)        : OmSq^T tile      (sq = OmB*OmB, pk f16)
//   n2 = mfma(ones_A, T1_B)     : n2[g=m] per LANE (1 rsq/tile, not 4)
//   OmPre = mfma(uI_A, OmB, Om) : diag(u)*Om + Om
// Cross-wave lam reduce: mfma(YpB,OmB) partials, write==read pattern,
// lane-contiguous b128 slots (conflict-free), double-buffered, 1 barrier/iter.

typedef float    f32x4 __attribute__((ext_vector_type(4)));
typedef _Float16 f16x4 __attribute__((ext_vector_type(4)));
typedef __fp16   h16x2 __attribute__((ext_vector_type(2)));

#define MUv 1e-3f
#define ROv 1e-3f

__device__ __forceinline__ f16x4 pack4(float a, float b, float c, float d) {
  h16x2 lo = __builtin_amdgcn_cvt_pkrtz(a, b);
  h16x2 hi = __builtin_amdgcn_cvt_pkrtz(c, d);
  union { struct { h16x2 lo, hi; } p; f16x4 v; } u;
  u.p.lo = lo; u.p.hi = hi;
  return u.v;
}

__device__ __forceinline__ f16x4 pack_dup(float a) {  // {a,a,a,a} as f16
  h16x2 d = __builtin_amdgcn_cvt_pkrtz(a, a);
  union { struct { h16x2 lo, hi; } p; f16x4 v; } u;
  u.p.lo = d; u.p.hi = d;
  return u.v;
}

__global__ __launch_bounds__(512) void gd_lagrange_kernel(
    const float* __restrict__ Yp,   // [128][16][1024]
    const float* __restrict__ Uk,   // [128][16][16]
    const float* __restrict__ Lm,   // [128][16][16]
    const float* __restrict__ Om0,  // [128][1024][16]
    const int* __restrict__ nitp,   // [1]
    float* __restrict__ out) {      // [128][1024][16]
  constexpr int S = 16, G = 1024;
  constexpr int YP_LD = 1028;

  const int wb   = blockIdx.x;
  const int tid  = threadIdx.x;
  const int wv   = tid >> 6;
  const int lane = tid & 63;
  const int q    = (tid >> 4) & 3;
  const int m    = tid & 15;
  const int g0   = wv * 128;

  __shared__ float ldsYp[S * YP_LD];
  __shared__ float ldsRed[2][8][256];   // lane-contiguous b128 slots
  __shared__ float ldsUk[S * S];
  __shared__ float ldsLm[S * S];

  const float* ypg = Yp + (size_t)wb * (S * G);

  // ---- stage Yp slice ----
  #pragma unroll
  for (int k = 0; k < 8; ++k) {
    int vi  = k * 512 + tid;
    f32x4 v = ((const f32x4*)ypg)[vi];
    int row = vi >> 8;
    int col = (vi & 255) * 4;
    *(f32x4*)&ldsYp[row * YP_LD + col] = v;
  }
  if (tid < 256) {
    ldsUk[tid] = Uk[wb * 256 + tid];
    ldsLm[tid] = Lm[wb * 256 + tid];
  }
  __syncthreads();

  // ---- static frags: identity (I[4q+e][m]) and ones ----
  f16x4 Ifrag, ones1;
  #pragma unroll
  for (int e = 0; e < 4; ++e) {
    Ifrag[e] = (4 * q + e == m) ? (_Float16)1.0f : (_Float16)0.0f;
    ones1[e] = (_Float16)1.0f;
  }

  // ---- static Yp fragments (f16) ----
  f16x4 YpA[8], YpB[8];
  #pragma unroll
  for (int t = 0; t < 8; ++t) {
    int gt = g0 + 16 * t;
    YpB[t] = pack4(ldsYp[m * YP_LD + gt + 4 * q + 0],
                   ldsYp[m * YP_LD + gt + 4 * q + 1],
                   ldsYp[m * YP_LD + gt + 4 * q + 2],
                   ldsYp[m * YP_LD + gt + 4 * q + 3]);
    YpA[t] = pack4(ldsYp[(4 * q + 0) * YP_LD + gt + m],
                   ldsYp[(4 * q + 1) * YP_LD + gt + m],
                   ldsYp[(4 * q + 2) * YP_LD + gt + m],
                   ldsYp[(4 * q + 3) * YP_LD + gt + m]);
  }

  // ---- Omega master (f32) ----
  f32x4 Om[8];
  const float* omg = Om0 + (size_t)wb * (G * S);
  #pragma unroll
  for (int t = 0; t < 8; ++t)
    #pragma unroll
    for (int r = 0; r < 4; ++r)
      Om[t][r] = omg[(g0 + 16 * t + 4 * q + r) * S + m];

  // ---- target: tgt[e] = (Uk@Lambda)[4q+e][m] ----
  f32x4 tgt;
  #pragma unroll
  for (int e = 0; e < 4; ++e) {
    float s = 0.f;
    for (int k = 0; k < 16; ++k)
      s += ldsUk[(4 * q + e) * 16 + k] * ldsLm[k * 16 + m];
    tgt[e] = s;
  }

  const int niter = nitp[0];
  const int rslot = lane * 4;
  constexpr float KLAM = -(MUv) * (ROv);   // lamN = -mu*lam master

  f32x4 lamN32 = {0.f, 0.f, 0.f, 0.f};
  f16x4 lamNB  = pack_dup(0.f);

  // norm-fold: OmPre = Om + u*Om via 3 MFMAs, u = -mu*rsq(n2_row)
  auto norm_fold = [&](const f16x4& omb, const f32x4& om) -> f32x4 {
    f32x4 z = {0.f, 0.f, 0.f, 0.f};
    f16x4 sq = omb * omb;                                          // pk f16
    f32x4 d1 = __builtin_amdgcn_mfma_f32_16x16x16f16(sq, Ifrag, z, 0, 0, 0);
    f16x4 t1 = pack4(d1[0], d1[1], d1[2], d1[3]);
    f32x4 n2 = __builtin_amdgcn_mfma_f32_16x16x16f16(ones1, t1, z, 0, 0, 0);
    float u  = -MUv * __builtin_amdgcn_rsqf(n2[0]);                // 1 rsq/tile
    f16x4 uI = Ifrag * pack_dup(u);                                // diag(u)
    return __builtin_amdgcn_mfma_f32_16x16x16f16(uI, omb, om, 0, 0, 0);
  };

  // ---- OmPre_0 and Phase B(0) ----
  f32x4 OmPre[8];
  f16x4 OmB[8];
  #pragma unroll
  for (int t = 0; t < 8; ++t) {
    OmB[t]   = pack4(Om[t][0], Om[t][1], Om[t][2], Om[t][3]);
    OmPre[t] = norm_fold(OmB[t], Om[t]);
  }
  {
    f32x4 a0 = {0.f, 0.f, 0.f, 0.f}, a1 = {0.f, 0.f, 0.f, 0.f};
    #pragma unroll
    for (int t = 0; t < 8; t += 2) {
      a0 = __builtin_amdgcn_mfma_f32_16x16x16f16(YpB[t], OmB[t], a0, 0, 0, 0);
      a1 = __builtin_amdgcn_mfma_f32_16x16x16f16(YpB[t + 1], OmB[t + 1], a1, 0, 0, 0);
    }
    *(f32x4*)&ldsRed[0][wv][rslot] = a0 + a1;
  }
  __syncthreads();
  f32x4 part[8];
  #pragma unroll
  for (int w2 = 0; w2 < 8; ++w2)
    part[w2] = *(const f32x4*)&ldsRed[0][w2][rslot];

  int wbuf = 1;
  for (int it = 0; it < niter; ++it) {
    // ===== HOT: Om_{i+1} = OmPre_i + YpT@lamN_i (fused C), Phase B =====
    f32x4 a0 = {0.f, 0.f, 0.f, 0.f}, a1 = {0.f, 0.f, 0.f, 0.f};
    #pragma unroll
    for (int t = 0; t < 8; ++t) {
      Om[t]  = __builtin_amdgcn_mfma_f32_16x16x16f16(YpA[t], lamNB, OmPre[t], 0, 0, 0);
      OmB[t] = pack4(Om[t][0], Om[t][1], Om[t][2], Om[t][3]);
      if (t & 1)
        a1 = __builtin_amdgcn_mfma_f32_16x16x16f16(YpB[t], OmB[t], a1, 0, 0, 0);
      else
        a0 = __builtin_amdgcn_mfma_f32_16x16x16f16(YpB[t], OmB[t], a0, 0, 0, 0);
    }
    *(f32x4*)&ldsRed[wbuf][wv][rslot] = a0 + a1;

    // lam_{i+1} from gsum_i (parts read last body; long complete)
    f32x4 gsum = ((part[0] + part[1]) + (part[2] + part[3])) +
                 ((part[4] + part[5]) + (part[6] + part[7]));
    f32x4 delta = gsum - tgt;
    #pragma unroll
    for (int e = 0; e < 4; ++e)
      lamN32[e] = fmaf(KLAM, delta[e], lamN32[e]);
    lamNB = pack4(lamN32[0], lamN32[1], lamN32[2], lamN32[3]);

    __syncthreads();

    // issue conflict-free cross-wave reads (consumed next body)
    #pragma unroll
    for (int w2 = 0; w2 < 8; ++w2)
      part[w2] = *(const f32x4*)&ldsRed[wbuf][w2][rslot];

    // ===== SHADOW: OmPre_{i+1} via MFMA norm-fold =====
    #pragma unroll
    for (int t = 0; t < 8; ++t)
      OmPre[t] = norm_fold(OmB[t], Om[t]);

    wbuf ^= 1;
  }

  // ---- store Omega ----
  float* og = out + (size_t)wb * (G * S);
  #pragma unroll
  for (int t = 0; t < 8; ++t)
    #pragma unroll
    for (int r = 0; r < 4; ++r)
      og[(g0 + 16 * t + 4 * q + r) * S + m] = Om[t][r];
}

extern "C" void kernel_launch(void* const* d_in, const int* in_sizes, int n_in,
                              void* d_out, int out_size, void* d_ws, size_t ws_size,
                              hipStream_t stream) {
  const float* Yp  = (const float*)d_in[0];
  const float* Uk  = (const float*)d_in[1];
  const float* Lm  = (const float*)d_in[2];
  const float* Om0 = (const float*)d_in[3];
  const int*   nit = (const int*)d_in[4];
  float* out = (float*)d_out;

  gd_lagrange_kernel<<<dim3(128), dim3(512), 0, stream>>>(Yp, Uk, Lm, Om0, nit, out);
}